// Round 8
// baseline (210.139 us; speedup 1.0000x reference)
//
#include <hip/hip_runtime.h>

// MoE top-2 SwiGLU (fp32 in/out, fp16 MFMA internal).
// Dispatches: memset(counts) -> prep_k (route + cvt x + transpose w13) ->
// gemm1 (128x(64g+64u), BK=32, silu fused, + absorbed w2-transpose blocks) ->
// gemm2 (128x64, BK=64, dbuf).
// h_ws uses SORTED layout (row = rowbase[e] + m): gemm1 stores m-contiguous,
// gemm2 A-staging streams sequentially (scatter deferred to gemm2 C-write).
// R18 changes (evidence in R17 post-mortem):
//  (a) MFMA operand swap in both GEMMs: compute C^T in regs so lanes hold 4
//      consecutive COLS -> vectorized epilogue (half4 / f32x4 stores) instead
//      of 32 scalar stores. Same math/accumulation order -> bit-identical.
//  (b) w2 transpose moved from prep into gemm1's grid (x=16..23, 1088 copy
//      blocks): gemm1 uses only 20% HBM, copy blocks fill the idle memory
//      pipe; w2t first read by gemm2 (ordering safe). Removes ~11us from the
//      serial prep path.
//  (c) prep transpose reverted to R10 algorithm (R17's 4x4-reg version
//      regressed +7.1us: residual R11 133.7 -> R17 140.8 w/ identical gemm2).
// Hidden-time note: all top-5 = gemm1 (~60) while residual 140.8 -> kernel sum
// ~178, graph/launch gaps ~23us (not addressable from kernel source).
// Grid orders (measured): gemm1 n0-fastest (m-fastest regressed 60->69.6 R9);
// gemm2 m-fastest (R9 ~16us). gemm2 config = R11 dbuf VERBATIM (best measured;
// BK=32 sbuf 143.4, 128x128 BK32 sbuf 152.9 both worse).
// gemm1: single-buffer BK=32 (R11 dbuf on gemm1 regressed 59.3->72.9; BK=64
// regressed 67.2 vs 61.7; XOR seg swizzle keeps gemm conflicts 0).

#define H_DIM 512
#define I_DIM 1024
#define E_NUM 8
#define P_PAIRS 16384
#define CAP P_PAIRS
#define MAX_TILES 136   // sum ceil(ne/128) <= 16384/128 + 7 = 135

// prep_k block ranges (w2 transpose lives in gemm1 now)
#define PREP_TW13 2048              // (2I/64=32) x (H/64=8) x E=8
#define PREP_CVT 2048               // 8192*512 / (256*8)
#define PREP_ROUTE 64               // 16384 / 256
#define PREP_BLOCKS (PREP_TW13 + PREP_CVT + PREP_ROUTE)

#define G1_NX 16                    // gemm1 n0 blocks
#define G1_TW2X 8                   // extra x-columns for w2 transpose
#define TW2_BLOCKS 1024             // (H/64=8) x (I/64=16) x E=8

typedef _Float16 half8 __attribute__((ext_vector_type(8)));
typedef _Float16 half4 __attribute__((ext_vector_type(4)));
typedef float f32x4 __attribute__((ext_vector_type(4)));
typedef unsigned int u32;
typedef const __attribute__((address_space(1))) u32* gas_t;
typedef __attribute__((address_space(3))) u32* las_t;

__device__ __forceinline__ void glds16(const void* g, void* l) {
  __builtin_amdgcn_global_load_lds((gas_t)g, (las_t)l, 16, 0, 0);
}

// derive (e, m0, ne, rowbase) for compact tile id ty; false if ty OOB
__device__ __forceinline__ bool tile_decode(const int* counts, int ty, int& e,
                                            int& m0, int& ne, int& rb) {
  int base = 0;
  rb = 0;
  for (e = 0; e < E_NUM; ++e) {
    ne = counts[e];
    const int nt = (ne + 127) >> 7;
    if (ty < base + nt) { m0 = (ty - base) << 7; return true; }
    base += nt;
    rb += ne;
  }
  return false;
}

// 64x64 f32->f16 transpose tile helper body (R10 algorithm, measured best):
// stage rows->LDS with scalar 2B writes, read cols as half8.
__device__ __forceinline__ void transpose64(const float* src, _Float16* dst,
                                            int R, int C, int r0, int c0,
                                            int tid, _Float16 (*tile)[72]) {
  {
    const int r = tid >> 4;
    const int c4 = (tid & 15) * 4;
    for (int pass = 0; pass < 4; ++pass) {
      f32x4 v = *(const f32x4*)(src + (size_t)(r0 + pass * 16 + r) * C + c0 + c4);
      for (int j = 0; j < 4; ++j) tile[c4 + j][pass * 16 + r] = (_Float16)v[j];
    }
  }
  __syncthreads();
  {
    const int c = tid >> 3;
    const int r8 = (tid & 7) * 8;
    for (int pass = 0; pass < 2; ++pass) {
      half8 h = *(const half8*)&tile[pass * 32 + c][r8];
      *(half8*)(dst + (size_t)(c0 + pass * 32 + c) * R + r0 + r8) = h;
    }
  }
}

// ------------------------------------------------------------------- prep ---
__global__ __launch_bounds__(256) void prep_k(
    const float* __restrict__ x, const int* __restrict__ idx,
    const float* __restrict__ w13,
    int* __restrict__ counts, int* __restrict__ lists,
    _Float16* __restrict__ xh, _Float16* __restrict__ w13t) {
  __shared__ __align__(16) _Float16 tile[64][72];  // 9216 B (route reuses head)
  const int b = blockIdx.x;
  const int tid = threadIdx.x;

  if (b < PREP_TW13) {
    const int R = H_DIM, C = 2 * I_DIM;
    const int e = b >> 8;
    const int c0 = (b & 31) * 64;
    const int r0 = ((b >> 5) & 7) * 64;
    transpose64(w13 + (size_t)e * R * C, w13t + (size_t)e * C * R,
                R, C, r0, c0, tid, tile);
  } else if (b < PREP_TW13 + PREP_CVT) {
    const int l = b - PREP_TW13;
    const size_t i = ((size_t)l * 256 + tid) * 8;
    f32x4 v0 = *(const f32x4*)(x + i);
    f32x4 v1 = *(const f32x4*)(x + i + 4);
    half8 h;
    for (int j = 0; j < 4; ++j) { h[j] = (_Float16)v0[j]; h[j + 4] = (_Float16)v1[j]; }
    *(half8*)(xh + i) = h;
  } else {
    int* lcnt = (int*)&tile[0][0];
    int* lbase = lcnt + E_NUM;
    const int l = b - (PREP_TW13 + PREP_CVT);
    if (tid < E_NUM) lcnt[tid] = 0;
    __syncthreads();
    const int p = l * 256 + tid;
    const int e = idx[p];
    const int r = atomicAdd(&lcnt[e], 1);
    __syncthreads();
    if (tid < E_NUM) lbase[tid] = atomicAdd(&counts[tid], lcnt[tid]);
    __syncthreads();
    lists[e * CAP + lbase[e] + r] = p;
  }
}

// ------------------------------------------------------------------ GEMM 1 ---
// Tile: 128 gathered pairs x (64 gate + 64 up cols), K=512, BK=32. 4 waves 2x2.
// Grid: x = n0 0..15 (fastest -> co-resident blocks share the random A-gather),
//       x = 16..23 -> absorbed w2-transpose blocks (fill idle memory pipe),
//       y = m-tile.
// Single-buffered 2-barrier loop (R11's explicit dbuf regressed 59.3->72.9).
// MFMA operands SWAPPED (R18): acc holds C^T -> lanes own 4 consecutive cols
// -> vectorized half4 epilogue. Output: sorted h_ws row rb + m0 + mrow.
__global__ __launch_bounds__(256) void gemm1_k(
    const _Float16* __restrict__ xh, const _Float16* __restrict__ w13t,
    const int* __restrict__ counts, const int* __restrict__ lists,
    _Float16* __restrict__ h_ws,
    const float* __restrict__ w2, _Float16* __restrict__ w2t) {
  __shared__ int rows[128];
  __shared__ __align__(16) _Float16 As[128 * 32];   // 8 KB
  __shared__ __align__(16) _Float16 Bgs[64 * 32];   // 4 KB
  __shared__ __align__(16) _Float16 Bus[64 * 32];   // 4 KB
  __shared__ __align__(16) _Float16 tile[64][72];   // 9 KB (transpose blocks)

  const int tid = threadIdx.x;

  if (blockIdx.x >= G1_NX) {
    // ---- absorbed w2 transpose: 1088 ids, use first 1024 ----
    const int id = (blockIdx.x - G1_NX) * MAX_TILES + blockIdx.y;
    if (id >= TW2_BLOCKS) return;
    const int R = I_DIM, C = H_DIM;
    const int e = id >> 7;
    const int l = id & 127;
    const int c0 = (l & 7) * 64;
    const int r0 = ((l >> 3) & 15) * 64;
    transpose64(w2 + (size_t)e * R * C, w2t + (size_t)e * C * R,
                R, C, r0, c0, tid, tile);
    return;
  }

  int e, m0, ne, rb;
  if (!tile_decode(counts, blockIdx.y, e, m0, ne, rb)) return;
  const int n0 = blockIdx.x * 64;

  if (tid < 128) {
    const int m = m0 + tid;
    rows[tid] = (m < ne) ? lists[e * CAP + m] : -1;
  }
  __syncthreads();

  // staging: row sr = tid/4, seg s4 = tid%4 (16B), XOR swizzle on global side
  const int sr = tid >> 2;
  const int s4 = tid & 3;
  const int segoff = ((s4 ^ ((sr >> 1) & 3)) * 8);
  const int pa0 = rows[sr];
  const int pa1 = rows[64 + sr];
  const int t0 = (pa0 >= 0) ? (pa0 >> 1) : 0;
  const int t1 = (pa1 >= 0) ? (pa1 >> 1) : 0;
  const _Float16* ga0 = xh + (size_t)t0 * H_DIM + segoff;
  const _Float16* ga1 = xh + (size_t)t1 * H_DIM + segoff;
  const _Float16* gbg = w13t + ((size_t)e * 2 * I_DIM + n0 + sr) * H_DIM + segoff;
  const _Float16* gbu = gbg + (size_t)I_DIM * H_DIM;
  _Float16* la0 = As + sr * 32 + s4 * 8;
  _Float16* la1 = As + (64 + sr) * 32 + s4 * 8;
  _Float16* lbg = Bgs + sr * 32 + s4 * 8;
  _Float16* lbu = Bus + sr * 32 + s4 * 8;

  const int lane = tid & 63;
  const int wid = tid >> 6;
  const int wm = wid & 1;
  const int wn = wid >> 1;
  const int fm = lane & 15;
  const int q = lane >> 4;
  int aoff[4], boff[2];
  for (int mi = 0; mi < 4; ++mi) {
    const int rA = wm * 64 + mi * 16 + fm;
    aoff[mi] = rA * 32 + ((q ^ ((rA >> 1) & 3)) * 8);
  }
  for (int ni = 0; ni < 2; ++ni) {
    const int cB = wn * 32 + ni * 16 + fm;
    boff[ni] = cB * 32 + ((q ^ ((cB >> 1) & 3)) * 8);
  }

  f32x4 accg[4][2] = {};
  f32x4 accu[4][2] = {};

  for (int k0 = 0; k0 < H_DIM; k0 += 32) {
    glds16(ga0 + k0, la0);
    glds16(ga1 + k0, la1);
    glds16(gbg + k0, lbg);
    glds16(gbu + k0, lbu);
    __syncthreads();

    half8 af[4], bg[2], bu[2];
    for (int mi = 0; mi < 4; ++mi) af[mi] = *(const half8*)&As[aoff[mi]];
    for (int ni = 0; ni < 2; ++ni) {
      bg[ni] = *(const half8*)&Bgs[boff[ni]];
      bu[ni] = *(const half8*)&Bus[boff[ni]];
    }
    // operands swapped: acc = C^T tile (lane fm = m-row, regs = 4 consec cols)
    for (int mi = 0; mi < 4; ++mi)
      for (int ni = 0; ni < 2; ++ni) {
        accg[mi][ni] = __builtin_amdgcn_mfma_f32_16x16x32_f16(bg[ni], af[mi], accg[mi][ni], 0, 0, 0);
        accu[mi][ni] = __builtin_amdgcn_mfma_f32_16x16x32_f16(bu[ni], af[mi], accu[mi][ni], 0, 0, 0);
      }
    __syncthreads();
  }

  // epilogue (C^T layout): lane fm = m-row, cols = ni*16 + q*4 + r
  for (int mi = 0; mi < 4; ++mi) {
    const int mrow = wm * 64 + mi * 16 + fm;
    if (m0 + mrow >= ne) continue;
    _Float16* hrow = h_ws + (size_t)(rb + m0 + mrow) * I_DIM + n0;
    for (int ni = 0; ni < 2; ++ni) {
      half4 hv;
      for (int r = 0; r < 4; ++r) {
        const float g = accg[mi][ni][r];
        const float u = accu[mi][ni][r];
        hv[r] = (_Float16)(g / (1.0f + __expf(-g)) * u);
      }
      *(half4*)&hrow[wn * 32 + ni * 16 + q * 4] = hv;
    }
  }
}

// ------------------------------------------------------------------ GEMM 2 ---
// R11 config (best measured residual): 128 sequential sorted-h rows x 64 out
// cols, K=1024, BK=64, 2-phase double-buffered, one barrier per K-step.
// Grid: x = m-tile (fastest), y = n0 [R9 evidence].
// MFMA operands SWAPPED (R18): vectorized f32x4 epilogue.
__global__ __launch_bounds__(256) void gemm2_k(
    const _Float16* __restrict__ h_ws, const _Float16* __restrict__ w2t,
    const int* __restrict__ counts, const int* __restrict__ lists,
    float* __restrict__ out) {
  int e, m0, ne, rb;
  if (!tile_decode(counts, blockIdx.x, e, m0, ne, rb)) return;
  const int n0 = blockIdx.y * 64;

  __shared__ int rows[128];
  __shared__ __align__(16) _Float16 As[2][128 * 64];  // 32 KB
  __shared__ __align__(16) _Float16 Bs[2][64 * 64];   // 16 KB

  const int tid = threadIdx.x;
  if (tid < 128) {
    const int m = m0 + tid;
    rows[tid] = (m < ne) ? lists[e * CAP + m] : -1;
  }
  // no barrier needed: rows[] first read in epilogue, loop barriers cover it

  const int s8 = tid & 7;
  const int sr8 = tid >> 3;  // 0..31
  const int sw = ((s8 ^ (sr8 & 7)) * 8);
  const _Float16* gA[4];
  int lA[4];
  for (int pa = 0; pa < 4; ++pa) {
    const int m = pa * 32 + sr8;
    int grow = rb + m0 + m;                       // sequential sorted rows
    if (grow > P_PAIRS - 1) grow = P_PAIRS - 1;   // clamp last-tile overrun
    gA[pa] = h_ws + (size_t)grow * I_DIM + sw;
    lA[pa] = m * 64 + s8 * 8;
  }
  const _Float16* gB[2];
  int lB[2];
  for (int pb = 0; pb < 2; ++pb) {
    const int n = pb * 32 + sr8;
    gB[pb] = w2t + ((size_t)e * H_DIM + n0 + n) * I_DIM + sw;
    lB[pb] = n * 64 + s8 * 8;
  }

  const int lane = tid & 63;
  const int wid = tid >> 6;
  const int wm = wid & 1;
  const int wn = wid >> 1;
  const int fm = lane & 15;
  const int q = lane >> 4;
  int aoff[2][4], boff[2][2];
  for (int ks = 0; ks < 2; ++ks) {
    for (int mi = 0; mi < 4; ++mi) {
      const int rA = wm * 64 + mi * 16 + fm;
      aoff[ks][mi] = rA * 64 + (((ks * 4 + q) ^ (rA & 7)) * 8);
    }
    for (int ni = 0; ni < 2; ++ni) {
      const int cB = wn * 32 + ni * 16 + fm;
      boff[ks][ni] = cB * 64 + (((ks * 4 + q) ^ (cB & 7)) * 8);
    }
  }

  f32x4 acc[4][2] = {};

#define G2_STAGE(buf, k0)                                  \
  do {                                                     \
    for (int pa = 0; pa < 4; ++pa)                         \
      glds16(gA[pa] + (k0), &As[buf][lA[pa]]);             \
    for (int pb = 0; pb < 2; ++pb)                         \
      glds16(gB[pb] + (k0), &Bs[buf][lB[pb]]);             \
  } while (0)

#define G2_COMPUTE(buf)                                                          \
  do {                                                                           \
    for (int ks = 0; ks < 2; ++ks) {                                             \
      half8 af[4], bf[2];                                                        \
      for (int mi = 0; mi < 4; ++mi)                                             \
        af[mi] = *(const half8*)&As[buf][aoff[ks][mi]];                          \
      for (int ni = 0; ni < 2; ++ni)                                             \
        bf[ni] = *(const half8*)&Bs[buf][boff[ks][ni]];                          \
      for (int mi = 0; mi < 4; ++mi)                                             \
        for (int ni = 0; ni < 2; ++ni)                                           \
          acc[mi][ni] = __builtin_amdgcn_mfma_f32_16x16x32_f16(                  \
              bf[ni], af[mi], acc[mi][ni], 0, 0, 0);                             \
    }                                                                            \
  } while (0)

  G2_STAGE(0, 0);
  __syncthreads();  // buf0 ready
  for (int k0 = 0; k0 < I_DIM; k0 += 128) {
    G2_STAGE(1, k0 + 64);     // k0+64 <= 960 always valid
    G2_COMPUTE(0);
    __syncthreads();
    if (k0 + 128 < I_DIM) G2_STAGE(0, k0 + 128);
    G2_COMPUTE(1);
    __syncthreads();
  }
#undef G2_STAGE
#undef G2_COMPUTE

  // epilogue (C^T layout): lane fm = out row, regs = 4 consecutive cols
  for (int mi = 0; mi < 4; ++mi) {
    const int p = rows[wm * 64 + mi * 16 + fm];
    if (p < 0) continue;
    float* orow = out + (size_t)p * H_DIM + n0;
    for (int ni = 0; ni < 2; ++ni)
      *(f32x4*)&orow[wn * 32 + ni * 16 + q * 4] = acc[mi][ni];
  }
}

// ------------------------------------------------------------------ launch ---
extern "C" void kernel_launch(void* const* d_in, const int* in_sizes, int n_in,
                              void* d_out, int out_size, void* d_ws, size_t ws_size,
                              hipStream_t stream) {
  const float* x = (const float*)d_in[0];
  const int* idx = (const int*)d_in[1];
  const float* w13 = (const float*)d_in[2];
  const float* w2 = (const float*)d_in[3];

  char* ws = (char*)d_ws;
  int* counts = (int*)ws;                  // 8 ints (pad to 2048)
  int* lists = (int*)(ws + 2048);          // 512 KB
  const size_t OFF_XH = 2048 + (size_t)E_NUM * CAP * 4;
  const size_t OFF_W13T = OFF_XH + (size_t)P_PAIRS / 2 * H_DIM * 2;          // +8.39 MB
  const size_t OFF_W2T = OFF_W13T + (size_t)E_NUM * 2 * I_DIM * H_DIM * 2;   // +16.78 MB
  const size_t OFF_H = OFF_W2T + (size_t)E_NUM * H_DIM * I_DIM * 2;          // +8.39 MB
  _Float16* xh = (_Float16*)(ws + OFF_XH);     // [B*S][H] fp16
  _Float16* w13t = (_Float16*)(ws + OFF_W13T); // [E][2I][H] fp16
  _Float16* w2t = (_Float16*)(ws + OFF_W2T);   // [E][H][I]  fp16
  _Float16* h_ws = (_Float16*)(ws + OFF_H);    // [P][I] fp16, SORTED rows (33.5 MB)

  hipMemsetAsync(d_ws, 0, 128, stream);  // zero expert counts
  prep_k<<<dim3(PREP_BLOCKS), 256, 0, stream>>>(x, idx, w13, counts, lists,
                                                xh, w13t);
  gemm1_k<<<dim3(G1_NX + G1_TW2X, MAX_TILES), 256, 0, stream>>>(
      xh, w13t, counts, lists, h_ws, w2, w2t);
  gemm2_k<<<dim3(MAX_TILES, H_DIM / 64), 256, 0, stream>>>(
      h_ws, w2t, counts, lists, (float*)d_out);
}

// Round 9
// 205.398 us; speedup vs baseline: 1.0231x; 1.0231x over previous
//
#include <hip/hip_runtime.h>

// MoE top-2 SwiGLU (fp32 in/out, fp16 MFMA internal).
// Dispatches: memset(counts) -> prep_k (route + cvt x + transpose w13 + w2,
// R10 algorithm) -> gemm1 (128x(64g+64u), BK=32, silu fused) ->
// gemm2 (128x64, BK=64, dbuf).
// h_ws uses SORTED layout (row = rowbase[e] + m): gemm1 stores m-contiguous,
// gemm2 A-staging streams sequentially (scatter deferred to gemm2 C-write).
// R19 = R17 structure + two evidenced deltas:
//  (1) prep transpose = R10 algorithm for BOTH w13 and w2 (R17's 4x4-reg
//      version regressed +7.1us: residual R11 133.7 -> R17 140.8, same gemm2).
//  (2) operand-swapped MFMA + vectorized epilogue in both GEMMs (verified
//      bit-identical in R18: absmax 0.001953125): acc holds C^T, lanes own 4
//      consecutive cols -> half4/f32x4 stores replace 32 scalar stores.
// R18's w2-transpose absorption into gemm1 REVERTED: LDS union 16896->26112
// dropped occupancy 26->17.7, MfmaUtil 24->18.9, gemm1 60->73.5, net -9us.
// Grid orders (measured): gemm1 n0-fastest (m-fastest regressed 60->69.6 R9);
// gemm2 m-fastest (R9 ~16us). gemm2 config = R11 dbuf VERBATIM (best measured;
// BK=32 sbuf 143.4, 128x128 BK32 sbuf 152.9 both worse; dbuf on gemm1
// regressed 59.3->72.9 — the two GEMMs are in different regimes).
// XOR seg swizzle on global side keeps gemm staging conflicts at 0.

#define H_DIM 512
#define I_DIM 1024
#define E_NUM 8
#define P_PAIRS 16384
#define CAP P_PAIRS
#define MAX_TILES 136   // sum ceil(ne/128) <= 16384/128 + 7 = 135

// prep_k block ranges
#define PREP_TW13 2048              // (2I/64=32) x (H/64=8) x E=8
#define PREP_TW2 1024               // (H/64=8) x (I/64=16) x E=8
#define PREP_CVT 2048               // 8192*512 / (256*8)
#define PREP_ROUTE 64               // 16384 / 256
#define PREP_BLOCKS (PREP_TW13 + PREP_TW2 + PREP_CVT + PREP_ROUTE)

typedef _Float16 half8 __attribute__((ext_vector_type(8)));
typedef _Float16 half4 __attribute__((ext_vector_type(4)));
typedef float f32x4 __attribute__((ext_vector_type(4)));
typedef unsigned int u32;
typedef const __attribute__((address_space(1))) u32* gas_t;
typedef __attribute__((address_space(3))) u32* las_t;

__device__ __forceinline__ void glds16(const void* g, void* l) {
  __builtin_amdgcn_global_load_lds((gas_t)g, (las_t)l, 16, 0, 0);
}

// derive (e, m0, ne, rowbase) for compact tile id ty; false if ty OOB
__device__ __forceinline__ bool tile_decode(const int* counts, int ty, int& e,
                                            int& m0, int& ne, int& rb) {
  int base = 0;
  rb = 0;
  for (e = 0; e < E_NUM; ++e) {
    ne = counts[e];
    const int nt = (ne + 127) >> 7;
    if (ty < base + nt) { m0 = (ty - base) << 7; return true; }
    base += nt;
    rb += ne;
  }
  return false;
}

// ------------------------------------------------------------------- prep ---
__global__ __launch_bounds__(256) void prep_k(
    const float* __restrict__ x, const int* __restrict__ idx,
    const float* __restrict__ w13, const float* __restrict__ w2,
    int* __restrict__ counts, int* __restrict__ lists,
    _Float16* __restrict__ xh, _Float16* __restrict__ w13t,
    _Float16* __restrict__ w2t) {
  __shared__ __align__(16) _Float16 tile[64][72];  // 9216 B (route reuses head)
  const int b = blockIdx.x;
  const int tid = threadIdx.x;

  if (b < PREP_TW13 + PREP_TW2) {
    const float* src;
    _Float16* dst;
    int R, C, c0, r0;
    if (b < PREP_TW13) {
      R = H_DIM; C = 2 * I_DIM;
      const int e = b >> 8;
      c0 = (b & 31) * 64;
      r0 = ((b >> 5) & 7) * 64;
      src = w13 + (size_t)e * R * C;
      dst = w13t + (size_t)e * C * R;
    } else {
      const int l = b - PREP_TW13;
      R = I_DIM; C = H_DIM;
      const int e = l >> 7;
      c0 = (l & 7) * 64;
      r0 = ((l >> 3) & 15) * 64;
      src = w2 + (size_t)e * R * C;
      dst = w2t + (size_t)e * C * R;
    }
    {
      const int r = tid >> 4;
      const int c4 = (tid & 15) * 4;
      for (int pass = 0; pass < 4; ++pass) {
        f32x4 v = *(const f32x4*)(src + (size_t)(r0 + pass * 16 + r) * C + c0 + c4);
        for (int j = 0; j < 4; ++j) tile[c4 + j][pass * 16 + r] = (_Float16)v[j];
      }
    }
    __syncthreads();
    {
      const int c = tid >> 3;
      const int r8 = (tid & 7) * 8;
      for (int pass = 0; pass < 2; ++pass) {
        half8 h = *(const half8*)&tile[pass * 32 + c][r8];
        *(half8*)(dst + (size_t)(c0 + pass * 32 + c) * R + r0 + r8) = h;
      }
    }
  } else if (b < PREP_TW13 + PREP_TW2 + PREP_CVT) {
    const int l = b - (PREP_TW13 + PREP_TW2);
    const size_t i = ((size_t)l * 256 + tid) * 8;
    f32x4 v0 = *(const f32x4*)(x + i);
    f32x4 v1 = *(const f32x4*)(x + i + 4);
    half8 h;
    for (int j = 0; j < 4; ++j) { h[j] = (_Float16)v0[j]; h[j + 4] = (_Float16)v1[j]; }
    *(half8*)(xh + i) = h;
  } else {
    int* lcnt = (int*)&tile[0][0];
    int* lbase = lcnt + E_NUM;
    const int l = b - (PREP_TW13 + PREP_TW2 + PREP_CVT);
    if (tid < E_NUM) lcnt[tid] = 0;
    __syncthreads();
    const int p = l * 256 + tid;
    const int e = idx[p];
    const int r = atomicAdd(&lcnt[e], 1);
    __syncthreads();
    if (tid < E_NUM) lbase[tid] = atomicAdd(&counts[tid], lcnt[tid]);
    __syncthreads();
    lists[e * CAP + lbase[e] + r] = p;
  }
}

// ------------------------------------------------------------------ GEMM 1 ---
// Tile: 128 gathered pairs x (64 gate + 64 up cols), K=512, BK=32. 4 waves 2x2.
// Grid: x = n0 (fastest -> co-resident blocks share the random A-gather),
//       y = m-tile.
// Single-buffered 2-barrier loop (R11's explicit dbuf regressed 59.3->72.9).
// MFMA operands SWAPPED: acc holds C^T -> lanes own 4 consecutive cols ->
// vectorized half4 epilogue (verified bit-identical, R18).
// Output: sorted h_ws row rb + m0 + mrow.
__global__ __launch_bounds__(256) void gemm1_k(
    const _Float16* __restrict__ xh, const _Float16* __restrict__ w13t,
    const int* __restrict__ counts, const int* __restrict__ lists,
    _Float16* __restrict__ h_ws) {
  int e, m0, ne, rb;
  if (!tile_decode(counts, blockIdx.y, e, m0, ne, rb)) return;
  const int n0 = blockIdx.x * 64;

  __shared__ int rows[128];
  __shared__ __align__(16) _Float16 As[128 * 32];   // 8 KB
  __shared__ __align__(16) _Float16 Bgs[64 * 32];   // 4 KB
  __shared__ __align__(16) _Float16 Bus[64 * 32];   // 4 KB

  const int tid = threadIdx.x;
  if (tid < 128) {
    const int m = m0 + tid;
    rows[tid] = (m < ne) ? lists[e * CAP + m] : -1;
  }
  __syncthreads();

  // staging: row sr = tid/4, seg s4 = tid%4 (16B), XOR swizzle on global side
  const int sr = tid >> 2;
  const int s4 = tid & 3;
  const int segoff = ((s4 ^ ((sr >> 1) & 3)) * 8);
  const int pa0 = rows[sr];
  const int pa1 = rows[64 + sr];
  const int t0 = (pa0 >= 0) ? (pa0 >> 1) : 0;
  const int t1 = (pa1 >= 0) ? (pa1 >> 1) : 0;
  const _Float16* ga0 = xh + (size_t)t0 * H_DIM + segoff;
  const _Float16* ga1 = xh + (size_t)t1 * H_DIM + segoff;
  const _Float16* gbg = w13t + ((size_t)e * 2 * I_DIM + n0 + sr) * H_DIM + segoff;
  const _Float16* gbu = gbg + (size_t)I_DIM * H_DIM;
  _Float16* la0 = As + sr * 32 + s4 * 8;
  _Float16* la1 = As + (64 + sr) * 32 + s4 * 8;
  _Float16* lbg = Bgs + sr * 32 + s4 * 8;
  _Float16* lbu = Bus + sr * 32 + s4 * 8;

  const int lane = tid & 63;
  const int wid = tid >> 6;
  const int wm = wid & 1;
  const int wn = wid >> 1;
  const int fm = lane & 15;
  const int q = lane >> 4;
  int aoff[4], boff[2];
  for (int mi = 0; mi < 4; ++mi) {
    const int rA = wm * 64 + mi * 16 + fm;
    aoff[mi] = rA * 32 + ((q ^ ((rA >> 1) & 3)) * 8);
  }
  for (int ni = 0; ni < 2; ++ni) {
    const int cB = wn * 32 + ni * 16 + fm;
    boff[ni] = cB * 32 + ((q ^ ((cB >> 1) & 3)) * 8);
  }

  f32x4 accg[4][2] = {};
  f32x4 accu[4][2] = {};

  for (int k0 = 0; k0 < H_DIM; k0 += 32) {
    glds16(ga0 + k0, la0);
    glds16(ga1 + k0, la1);
    glds16(gbg + k0, lbg);
    glds16(gbu + k0, lbu);
    __syncthreads();

    half8 af[4], bg[2], bu[2];
    for (int mi = 0; mi < 4; ++mi) af[mi] = *(const half8*)&As[aoff[mi]];
    for (int ni = 0; ni < 2; ++ni) {
      bg[ni] = *(const half8*)&Bgs[boff[ni]];
      bu[ni] = *(const half8*)&Bus[boff[ni]];
    }
    // operands swapped: acc = C^T tile (lane fm = m-row, regs = 4 consec cols)
    for (int mi = 0; mi < 4; ++mi)
      for (int ni = 0; ni < 2; ++ni) {
        accg[mi][ni] = __builtin_amdgcn_mfma_f32_16x16x32_f16(bg[ni], af[mi], accg[mi][ni], 0, 0, 0);
        accu[mi][ni] = __builtin_amdgcn_mfma_f32_16x16x32_f16(bu[ni], af[mi], accu[mi][ni], 0, 0, 0);
      }
    __syncthreads();
  }

  // epilogue (C^T layout): lane fm = m-row, cols = ni*16 + q*4 + r
  for (int mi = 0; mi < 4; ++mi) {
    const int mrow = wm * 64 + mi * 16 + fm;
    if (m0 + mrow >= ne) continue;
    _Float16* hrow = h_ws + (size_t)(rb + m0 + mrow) * I_DIM + n0;
    for (int ni = 0; ni < 2; ++ni) {
      half4 hv;
      for (int r = 0; r < 4; ++r) {
        const float g = accg[mi][ni][r];
        const float u = accu[mi][ni][r];
        hv[r] = (_Float16)(g / (1.0f + __expf(-g)) * u);
      }
      *(half4*)&hrow[wn * 32 + ni * 16 + q * 4] = hv;
    }
  }
}

// ------------------------------------------------------------------ GEMM 2 ---
// R11 config (best measured residual): 128 sequential sorted-h rows x 64 out
// cols, K=1024, BK=64, 2-phase double-buffered, one barrier per K-step.
// Grid: x = m-tile (fastest), y = n0 [R9 evidence].
// MFMA operands SWAPPED: vectorized f32x4 epilogue (verified, R18).
__global__ __launch_bounds__(256) void gemm2_k(
    const _Float16* __restrict__ h_ws, const _Float16* __restrict__ w2t,
    const int* __restrict__ counts, const int* __restrict__ lists,
    float* __restrict__ out) {
  int e, m0, ne, rb;
  if (!tile_decode(counts, blockIdx.x, e, m0, ne, rb)) return;
  const int n0 = blockIdx.y * 64;

  __shared__ int rows[128];
  __shared__ __align__(16) _Float16 As[2][128 * 64];  // 32 KB
  __shared__ __align__(16) _Float16 Bs[2][64 * 64];   // 16 KB

  const int tid = threadIdx.x;
  if (tid < 128) {
    const int m = m0 + tid;
    rows[tid] = (m < ne) ? lists[e * CAP + m] : -1;
  }
  // no barrier needed: rows[] first read in epilogue, loop barriers cover it

  const int s8 = tid & 7;
  const int sr8 = tid >> 3;  // 0..31
  const int sw = ((s8 ^ (sr8 & 7)) * 8);
  const _Float16* gA[4];
  int lA[4];
  for (int pa = 0; pa < 4; ++pa) {
    const int m = pa * 32 + sr8;
    int grow = rb + m0 + m;                       // sequential sorted rows
    if (grow > P_PAIRS - 1) grow = P_PAIRS - 1;   // clamp last-tile overrun
    gA[pa] = h_ws + (size_t)grow * I_DIM + sw;
    lA[pa] = m * 64 + s8 * 8;
  }
  const _Float16* gB[2];
  int lB[2];
  for (int pb = 0; pb < 2; ++pb) {
    const int n = pb * 32 + sr8;
    gB[pb] = w2t + ((size_t)e * H_DIM + n0 + n) * I_DIM + sw;
    lB[pb] = n * 64 + s8 * 8;
  }

  const int lane = tid & 63;
  const int wid = tid >> 6;
  const int wm = wid & 1;
  const int wn = wid >> 1;
  const int fm = lane & 15;
  const int q = lane >> 4;
  int aoff[2][4], boff[2][2];
  for (int ks = 0; ks < 2; ++ks) {
    for (int mi = 0; mi < 4; ++mi) {
      const int rA = wm * 64 + mi * 16 + fm;
      aoff[ks][mi] = rA * 64 + (((ks * 4 + q) ^ (rA & 7)) * 8);
    }
    for (int ni = 0; ni < 2; ++ni) {
      const int cB = wn * 32 + ni * 16 + fm;
      boff[ks][ni] = cB * 64 + (((ks * 4 + q) ^ (cB & 7)) * 8);
    }
  }

  f32x4 acc[4][2] = {};

#define G2_STAGE(buf, k0)                                  \
  do {                                                     \
    for (int pa = 0; pa < 4; ++pa)                         \
      glds16(gA[pa] + (k0), &As[buf][lA[pa]]);             \
    for (int pb = 0; pb < 2; ++pb)                         \
      glds16(gB[pb] + (k0), &Bs[buf][lB[pb]]);             \
  } while (0)

#define G2_COMPUTE(buf)                                                          \
  do {                                                                           \
    for (int ks = 0; ks < 2; ++ks) {                                             \
      half8 af[4], bf[2];                                                        \
      for (int mi = 0; mi < 4; ++mi)                                             \
        af[mi] = *(const half8*)&As[buf][aoff[ks][mi]];                          \
      for (int ni = 0; ni < 2; ++ni)                                             \
        bf[ni] = *(const half8*)&Bs[buf][boff[ks][ni]];                          \
      for (int mi = 0; mi < 4; ++mi)                                             \
        for (int ni = 0; ni < 2; ++ni)                                           \
          acc[mi][ni] = __builtin_amdgcn_mfma_f32_16x16x32_f16(                  \
              bf[ni], af[mi], acc[mi][ni], 0, 0, 0);                             \
    }                                                                            \
  } while (0)

  G2_STAGE(0, 0);
  __syncthreads();  // buf0 ready
  for (int k0 = 0; k0 < I_DIM; k0 += 128) {
    G2_STAGE(1, k0 + 64);     // k0+64 <= 960 always valid
    G2_COMPUTE(0);
    __syncthreads();
    if (k0 + 128 < I_DIM) G2_STAGE(0, k0 + 128);
    G2_COMPUTE(1);
    __syncthreads();
  }
#undef G2_STAGE
#undef G2_COMPUTE

  // epilogue (C^T layout): lane fm = out row, regs = 4 consecutive cols
  for (int mi = 0; mi < 4; ++mi) {
    const int p = rows[wm * 64 + mi * 16 + fm];
    if (p < 0) continue;
    float* orow = out + (size_t)p * H_DIM + n0;
    for (int ni = 0; ni < 2; ++ni)
      *(f32x4*)&orow[wn * 32 + ni * 16 + q * 4] = acc[mi][ni];
  }
}

// ------------------------------------------------------------------ launch ---
extern "C" void kernel_launch(void* const* d_in, const int* in_sizes, int n_in,
                              void* d_out, int out_size, void* d_ws, size_t ws_size,
                              hipStream_t stream) {
  const float* x = (const float*)d_in[0];
  const int* idx = (const int*)d_in[1];
  const float* w13 = (const float*)d_in[2];
  const float* w2 = (const float*)d_in[3];

  char* ws = (char*)d_ws;
  int* counts = (int*)ws;                  // 8 ints (pad to 2048)
  int* lists = (int*)(ws + 2048);          // 512 KB
  const size_t OFF_XH = 2048 + (size_t)E_NUM * CAP * 4;
  const size_t OFF_W13T = OFF_XH + (size_t)P_PAIRS / 2 * H_DIM * 2;          // +8.39 MB
  const size_t OFF_W2T = OFF_W13T + (size_t)E_NUM * 2 * I_DIM * H_DIM * 2;   // +16.78 MB
  const size_t OFF_H = OFF_W2T + (size_t)E_NUM * H_DIM * I_DIM * 2;          // +8.39 MB
  _Float16* xh = (_Float16*)(ws + OFF_XH);     // [B*S][H] fp16
  _Float16* w13t = (_Float16*)(ws + OFF_W13T); // [E][2I][H] fp16
  _Float16* w2t = (_Float16*)(ws + OFF_W2T);   // [E][H][I]  fp16
  _Float16* h_ws = (_Float16*)(ws + OFF_H);    // [P][I] fp16, SORTED rows (33.5 MB)

  hipMemsetAsync(d_ws, 0, 128, stream);  // zero expert counts
  prep_k<<<dim3(PREP_BLOCKS), 256, 0, stream>>>(x, idx, w13, w2, counts, lists,
                                                xh, w13t, w2t);
  gemm1_k<<<dim3(I_DIM / 64, MAX_TILES), 256, 0, stream>>>(
      xh, w13t, counts, lists, h_ws);
  gemm2_k<<<dim3(MAX_TILES, H_DIM / 64), 256, 0, stream>>>(
      h_ws, w2t, counts, lists, (float*)d_out);
}

// Round 10
// 196.631 us; speedup vs baseline: 1.0687x; 1.0446x over previous
//
#include <hip/hip_runtime.h>

// MoE top-2 SwiGLU (fp32 in/out, fp16 MFMA internal).
// Dispatches: memset(counts) -> prep_k (route + cvt x + transpose w13 + w2,
// R10 algorithm) -> gemm1 (128x(64g+64u), BK=32, silu fused) ->
// gemm2 (128x64, BK=64, dbuf, swapped-MFMA f32x4 epilogue).
// h_ws uses SORTED layout (row = rowbase[e] + m): gemm1 stores m-contiguous,
// gemm2 A-staging streams sequentially (scatter deferred to gemm2 C-write).
// R20 = R19 with gemm1 reverted to its measured-best form (R12/R17: 60.3us,
// VGPR 76, occ 26.9, x4 measurements). R19 isolated the swap epilogue as the
// gemm1 regressor (60.3->72.7, VGPR 76->88, occ 26.9->17.4): per-lane half4
// stores go to 16 DIFFERENT rows (2KB stride) -> de-coalesced 8B scatters,
// vs old scalar-but-coalesced 32B segments. Lesson: vectorize-per-lane !=
// coalesce-per-wave for fp16 row-major output.
// gemm2 KEEPS the swap (fp32 f32x4 16B stores; residual 132.7 = best ever;
// scatter via rows[] exists either way).
// prep = R10 transpose for both weights (R17's 4x4-reg version regressed
// +7.1us; reverted in R19, residual confirmed -7..8).
// Grid orders (measured): gemm1 n0-fastest (m-fastest regressed 60->69.6 R9);
// gemm2 m-fastest (R9 ~16us). gemm2 config = R11 dbuf (best measured; BK=32
// sbuf 143.4, 128x128 BK32 sbuf 152.9 worse; dbuf on gemm1 regressed
// 59.3->72.9 — the two GEMMs are in different regimes).
// R18's w2-transpose absorption into gemm1: REVERTED (LDS union dropped
// occupancy 26->17.7, gemm1 60->73.5). XOR seg swizzle keeps conflicts 0.

#define H_DIM 512
#define I_DIM 1024
#define E_NUM 8
#define P_PAIRS 16384
#define CAP P_PAIRS
#define MAX_TILES 136   // sum ceil(ne/128) <= 16384/128 + 7 = 135

// prep_k block ranges
#define PREP_TW13 2048              // (2I/64=32) x (H/64=8) x E=8
#define PREP_TW2 1024               // (H/64=8) x (I/64=16) x E=8
#define PREP_CVT 2048               // 8192*512 / (256*8)
#define PREP_ROUTE 64               // 16384 / 256
#define PREP_BLOCKS (PREP_TW13 + PREP_TW2 + PREP_CVT + PREP_ROUTE)

typedef _Float16 half8 __attribute__((ext_vector_type(8)));
typedef float f32x4 __attribute__((ext_vector_type(4)));
typedef unsigned int u32;
typedef const __attribute__((address_space(1))) u32* gas_t;
typedef __attribute__((address_space(3))) u32* las_t;

__device__ __forceinline__ void glds16(const void* g, void* l) {
  __builtin_amdgcn_global_load_lds((gas_t)g, (las_t)l, 16, 0, 0);
}

// derive (e, m0, ne, rowbase) for compact tile id ty; false if ty OOB
__device__ __forceinline__ bool tile_decode(const int* counts, int ty, int& e,
                                            int& m0, int& ne, int& rb) {
  int base = 0;
  rb = 0;
  for (e = 0; e < E_NUM; ++e) {
    ne = counts[e];
    const int nt = (ne + 127) >> 7;
    if (ty < base + nt) { m0 = (ty - base) << 7; return true; }
    base += nt;
    rb += ne;
  }
  return false;
}

// ------------------------------------------------------------------- prep ---
__global__ __launch_bounds__(256) void prep_k(
    const float* __restrict__ x, const int* __restrict__ idx,
    const float* __restrict__ w13, const float* __restrict__ w2,
    int* __restrict__ counts, int* __restrict__ lists,
    _Float16* __restrict__ xh, _Float16* __restrict__ w13t,
    _Float16* __restrict__ w2t) {
  __shared__ __align__(16) _Float16 tile[64][72];  // 9216 B (route reuses head)
  const int b = blockIdx.x;
  const int tid = threadIdx.x;

  if (b < PREP_TW13 + PREP_TW2) {
    const float* src;
    _Float16* dst;
    int R, C, c0, r0;
    if (b < PREP_TW13) {
      R = H_DIM; C = 2 * I_DIM;
      const int e = b >> 8;
      c0 = (b & 31) * 64;
      r0 = ((b >> 5) & 7) * 64;
      src = w13 + (size_t)e * R * C;
      dst = w13t + (size_t)e * C * R;
    } else {
      const int l = b - PREP_TW13;
      R = I_DIM; C = H_DIM;
      const int e = l >> 7;
      c0 = (l & 7) * 64;
      r0 = ((l >> 3) & 15) * 64;
      src = w2 + (size_t)e * R * C;
      dst = w2t + (size_t)e * C * R;
    }
    {
      const int r = tid >> 4;
      const int c4 = (tid & 15) * 4;
      for (int pass = 0; pass < 4; ++pass) {
        f32x4 v = *(const f32x4*)(src + (size_t)(r0 + pass * 16 + r) * C + c0 + c4);
        for (int j = 0; j < 4; ++j) tile[c4 + j][pass * 16 + r] = (_Float16)v[j];
      }
    }
    __syncthreads();
    {
      const int c = tid >> 3;
      const int r8 = (tid & 7) * 8;
      for (int pass = 0; pass < 2; ++pass) {
        half8 h = *(const half8*)&tile[pass * 32 + c][r8];
        *(half8*)(dst + (size_t)(c0 + pass * 32 + c) * R + r0 + r8) = h;
      }
    }
  } else if (b < PREP_TW13 + PREP_TW2 + PREP_CVT) {
    const int l = b - (PREP_TW13 + PREP_TW2);
    const size_t i = ((size_t)l * 256 + tid) * 8;
    f32x4 v0 = *(const f32x4*)(x + i);
    f32x4 v1 = *(const f32x4*)(x + i + 4);
    half8 h;
    for (int j = 0; j < 4; ++j) { h[j] = (_Float16)v0[j]; h[j + 4] = (_Float16)v1[j]; }
    *(half8*)(xh + i) = h;
  } else {
    int* lcnt = (int*)&tile[0][0];
    int* lbase = lcnt + E_NUM;
    const int l = b - (PREP_TW13 + PREP_TW2 + PREP_CVT);
    if (tid < E_NUM) lcnt[tid] = 0;
    __syncthreads();
    const int p = l * 256 + tid;
    const int e = idx[p];
    const int r = atomicAdd(&lcnt[e], 1);
    __syncthreads();
    if (tid < E_NUM) lbase[tid] = atomicAdd(&counts[tid], lcnt[tid]);
    __syncthreads();
    lists[e * CAP + lbase[e] + r] = p;
  }
}

// ------------------------------------------------------------------ GEMM 1 ---
// Tile: 128 gathered pairs x (64 gate + 64 up cols), K=512, BK=32. 4 waves 2x2.
// Grid: x = n0 (fastest -> co-resident blocks share the random A-gather),
//       y = m-tile.
// Single-buffered 2-barrier loop; NON-swapped MFMA + scalar-coalesced
// epilogue (measured best x4: 60.3us / VGPR 76 / occ 26.9; swap epilogue
// regressed to 72.7 — R19). Output: sorted h_ws row rb + m0 + mrow.
__global__ __launch_bounds__(256) void gemm1_k(
    const _Float16* __restrict__ xh, const _Float16* __restrict__ w13t,
    const int* __restrict__ counts, const int* __restrict__ lists,
    _Float16* __restrict__ h_ws) {
  int e, m0, ne, rb;
  if (!tile_decode(counts, blockIdx.y, e, m0, ne, rb)) return;
  const int n0 = blockIdx.x * 64;

  __shared__ int rows[128];
  __shared__ __align__(16) _Float16 As[128 * 32];   // 8 KB
  __shared__ __align__(16) _Float16 Bgs[64 * 32];   // 4 KB
  __shared__ __align__(16) _Float16 Bus[64 * 32];   // 4 KB

  const int tid = threadIdx.x;
  if (tid < 128) {
    const int m = m0 + tid;
    rows[tid] = (m < ne) ? lists[e * CAP + m] : -1;
  }
  __syncthreads();

  // staging: row sr = tid/4, seg s4 = tid%4 (16B), XOR swizzle on global side
  const int sr = tid >> 2;
  const int s4 = tid & 3;
  const int segoff = ((s4 ^ ((sr >> 1) & 3)) * 8);
  const int pa0 = rows[sr];
  const int pa1 = rows[64 + sr];
  const int t0 = (pa0 >= 0) ? (pa0 >> 1) : 0;
  const int t1 = (pa1 >= 0) ? (pa1 >> 1) : 0;
  const _Float16* ga0 = xh + (size_t)t0 * H_DIM + segoff;
  const _Float16* ga1 = xh + (size_t)t1 * H_DIM + segoff;
  const _Float16* gbg = w13t + ((size_t)e * 2 * I_DIM + n0 + sr) * H_DIM + segoff;
  const _Float16* gbu = gbg + (size_t)I_DIM * H_DIM;
  _Float16* la0 = As + sr * 32 + s4 * 8;
  _Float16* la1 = As + (64 + sr) * 32 + s4 * 8;
  _Float16* lbg = Bgs + sr * 32 + s4 * 8;
  _Float16* lbu = Bus + sr * 32 + s4 * 8;

  const int lane = tid & 63;
  const int wid = tid >> 6;
  const int wm = wid & 1;
  const int wn = wid >> 1;
  const int fm = lane & 15;
  const int q = lane >> 4;
  int aoff[4], boff[2];
  for (int mi = 0; mi < 4; ++mi) {
    const int rA = wm * 64 + mi * 16 + fm;
    aoff[mi] = rA * 32 + ((q ^ ((rA >> 1) & 3)) * 8);
  }
  for (int ni = 0; ni < 2; ++ni) {
    const int cB = wn * 32 + ni * 16 + fm;
    boff[ni] = cB * 32 + ((q ^ ((cB >> 1) & 3)) * 8);
  }

  f32x4 accg[4][2] = {};
  f32x4 accu[4][2] = {};

  for (int k0 = 0; k0 < H_DIM; k0 += 32) {
    glds16(ga0 + k0, la0);
    glds16(ga1 + k0, la1);
    glds16(gbg + k0, lbg);
    glds16(gbu + k0, lbu);
    __syncthreads();

    half8 af[4], bg[2], bu[2];
    for (int mi = 0; mi < 4; ++mi) af[mi] = *(const half8*)&As[aoff[mi]];
    for (int ni = 0; ni < 2; ++ni) {
      bg[ni] = *(const half8*)&Bgs[boff[ni]];
      bu[ni] = *(const half8*)&Bus[boff[ni]];
    }
    for (int mi = 0; mi < 4; ++mi)
      for (int ni = 0; ni < 2; ++ni) {
        accg[mi][ni] = __builtin_amdgcn_mfma_f32_16x16x32_f16(af[mi], bg[ni], accg[mi][ni], 0, 0, 0);
        accu[mi][ni] = __builtin_amdgcn_mfma_f32_16x16x32_f16(af[mi], bu[ni], accu[mi][ni], 0, 0, 0);
      }
    __syncthreads();
  }

  // epilogue: C/D layout col=lane&15, row=q*4+reg; silu(g)*u -> sorted h_ws
  // (scalar 2B stores, but fm=0..15 lanes cover 16 consecutive cols -> 32B
  // coalesced segments per lane-group; measured better than per-lane half4)
  for (int mi = 0; mi < 4; ++mi)
    for (int r = 0; r < 4; ++r) {
      const int mrow = wm * 64 + mi * 16 + q * 4 + r;
      if (m0 + mrow >= ne) continue;
      _Float16* hrow = h_ws + (size_t)(rb + m0 + mrow) * I_DIM + n0;
      for (int ni = 0; ni < 2; ++ni) {
        const int c = wn * 32 + ni * 16 + fm;
        const float g = accg[mi][ni][r];
        const float u = accu[mi][ni][r];
        hrow[c] = (_Float16)(g / (1.0f + __expf(-g)) * u);
      }
    }
}

// ------------------------------------------------------------------ GEMM 2 ---
// R11 config (best measured residual): 128 sequential sorted-h rows x 64 out
// cols, K=1024, BK=64, 2-phase double-buffered, one barrier per K-step.
// Grid: x = m-tile (fastest), y = n0 [R9 evidence].
// MFMA operands SWAPPED: vectorized f32x4 epilogue (R19 residual 132.7 =
// best ever; fp32 16B stores, scatter via rows[] exists either way).
__global__ __launch_bounds__(256) void gemm2_k(
    const _Float16* __restrict__ h_ws, const _Float16* __restrict__ w2t,
    const int* __restrict__ counts, const int* __restrict__ lists,
    float* __restrict__ out) {
  int e, m0, ne, rb;
  if (!tile_decode(counts, blockIdx.x, e, m0, ne, rb)) return;
  const int n0 = blockIdx.y * 64;

  __shared__ int rows[128];
  __shared__ __align__(16) _Float16 As[2][128 * 64];  // 32 KB
  __shared__ __align__(16) _Float16 Bs[2][64 * 64];   // 16 KB

  const int tid = threadIdx.x;
  if (tid < 128) {
    const int m = m0 + tid;
    rows[tid] = (m < ne) ? lists[e * CAP + m] : -1;
  }
  // no barrier needed: rows[] first read in epilogue, loop barriers cover it

  const int s8 = tid & 7;
  const int sr8 = tid >> 3;  // 0..31
  const int sw = ((s8 ^ (sr8 & 7)) * 8);
  const _Float16* gA[4];
  int lA[4];
  for (int pa = 0; pa < 4; ++pa) {
    const int m = pa * 32 + sr8;
    int grow = rb + m0 + m;                       // sequential sorted rows
    if (grow > P_PAIRS - 1) grow = P_PAIRS - 1;   // clamp last-tile overrun
    gA[pa] = h_ws + (size_t)grow * I_DIM + sw;
    lA[pa] = m * 64 + s8 * 8;
  }
  const _Float16* gB[2];
  int lB[2];
  for (int pb = 0; pb < 2; ++pb) {
    const int n = pb * 32 + sr8;
    gB[pb] = w2t + ((size_t)e * H_DIM + n0 + n) * I_DIM + sw;
    lB[pb] = n * 64 + s8 * 8;
  }

  const int lane = tid & 63;
  const int wid = tid >> 6;
  const int wm = wid & 1;
  const int wn = wid >> 1;
  const int fm = lane & 15;
  const int q = lane >> 4;
  int aoff[2][4], boff[2][2];
  for (int ks = 0; ks < 2; ++ks) {
    for (int mi = 0; mi < 4; ++mi) {
      const int rA = wm * 64 + mi * 16 + fm;
      aoff[ks][mi] = rA * 64 + (((ks * 4 + q) ^ (rA & 7)) * 8);
    }
    for (int ni = 0; ni < 2; ++ni) {
      const int cB = wn * 32 + ni * 16 + fm;
      boff[ks][ni] = cB * 64 + (((ks * 4 + q) ^ (cB & 7)) * 8);
    }
  }

  f32x4 acc[4][2] = {};

#define G2_STAGE(buf, k0)                                  \
  do {                                                     \
    for (int pa = 0; pa < 4; ++pa)                         \
      glds16(gA[pa] + (k0), &As[buf][lA[pa]]);             \
    for (int pb = 0; pb < 2; ++pb)                         \
      glds16(gB[pb] + (k0), &Bs[buf][lB[pb]]);             \
  } while (0)

#define G2_COMPUTE(buf)                                                          \
  do {                                                                           \
    for (int ks = 0; ks < 2; ++ks) {                                             \
      half8 af[4], bf[2];                                                        \
      for (int mi = 0; mi < 4; ++mi)                                             \
        af[mi] = *(const half8*)&As[buf][aoff[ks][mi]];                          \
      for (int ni = 0; ni < 2; ++ni)                                             \
        bf[ni] = *(const half8*)&Bs[buf][boff[ks][ni]];                          \
      for (int mi = 0; mi < 4; ++mi)                                             \
        for (int ni = 0; ni < 2; ++ni)                                           \
          acc[mi][ni] = __builtin_amdgcn_mfma_f32_16x16x32_f16(                  \
              bf[ni], af[mi], acc[mi][ni], 0, 0, 0);                             \
    }                                                                            \
  } while (0)

  G2_STAGE(0, 0);
  __syncthreads();  // buf0 ready
  for (int k0 = 0; k0 < I_DIM; k0 += 128) {
    G2_STAGE(1, k0 + 64);     // k0+64 <= 960 always valid
    G2_COMPUTE(0);
    __syncthreads();
    if (k0 + 128 < I_DIM) G2_STAGE(0, k0 + 128);
    G2_COMPUTE(1);
    __syncthreads();
  }
#undef G2_STAGE
#undef G2_COMPUTE

  // epilogue (C^T layout): lane fm = out row, regs = 4 consecutive cols
  for (int mi = 0; mi < 4; ++mi) {
    const int p = rows[wm * 64 + mi * 16 + fm];
    if (p < 0) continue;
    float* orow = out + (size_t)p * H_DIM + n0;
    for (int ni = 0; ni < 2; ++ni)
      *(f32x4*)&orow[wn * 32 + ni * 16 + q * 4] = acc[mi][ni];
  }
}

// ------------------------------------------------------------------ launch ---
extern "C" void kernel_launch(void* const* d_in, const int* in_sizes, int n_in,
                              void* d_out, int out_size, void* d_ws, size_t ws_size,
                              hipStream_t stream) {
  const float* x = (const float*)d_in[0];
  const int* idx = (const int*)d_in[1];
  const float* w13 = (const float*)d_in[2];
  const float* w2 = (const float*)d_in[3];

  char* ws = (char*)d_ws;
  int* counts = (int*)ws;                  // 8 ints (pad to 2048)
  int* lists = (int*)(ws + 2048);          // 512 KB
  const size_t OFF_XH = 2048 + (size_t)E_NUM * CAP * 4;
  const size_t OFF_W13T = OFF_XH + (size_t)P_PAIRS / 2 * H_DIM * 2;          // +8.39 MB
  const size_t OFF_W2T = OFF_W13T + (size_t)E_NUM * 2 * I_DIM * H_DIM * 2;   // +16.78 MB
  const size_t OFF_H = OFF_W2T + (size_t)E_NUM * H_DIM * I_DIM * 2;          // +8.39 MB
  _Float16* xh = (_Float16*)(ws + OFF_XH);     // [B*S][H] fp16
  _Float16* w13t = (_Float16*)(ws + OFF_W13T); // [E][2I][H] fp16
  _Float16* w2t = (_Float16*)(ws + OFF_W2T);   // [E][H][I]  fp16
  _Float16* h_ws = (_Float16*)(ws + OFF_H);    // [P][I] fp16, SORTED rows (33.5 MB)

  hipMemsetAsync(d_ws, 0, 128, stream);  // zero expert counts
  prep_k<<<dim3(PREP_BLOCKS), 256, 0, stream>>>(x, idx, w13, w2, counts, lists,
                                                xh, w13t, w2t);
  gemm1_k<<<dim3(I_DIM / 64, MAX_TILES), 256, 0, stream>>>(
      xh, w13t, counts, lists, h_ws);
  gemm2_k<<<dim3(MAX_TILES, H_DIM / 64), 256, 0, stream>>>(
      h_ws, w2t, counts, lists, (float*)d_out);
}